// Round 23
// baseline (154.231 us; speedup 1.0000x reference)
//
#include <hip/hip_runtime.h>
#include <hip/hip_bf16.h>

typedef __attribute__((ext_vector_type(8))) short bf16x8;
typedef __attribute__((ext_vector_type(4))) short bf16x4;
typedef __attribute__((ext_vector_type(4))) float f32x4;
typedef __attribute__((ext_vector_type(16))) float f32x16;

#define NB 4
#define NL 2048
#define NH 16
#define NE 64
#define HE (NH*NE)
#define QW 32
#define QBLK 128
#define NQT (NL/QBLK)      // 16
#define NBH 64
#define NKT 32             // kv64 tiles per (b,h)
#define TILE_IMG 16384     // 8KB K + 8KB V^T per (bh, kv-tile)
#define WS_NEED ((size_t)NBH * NKT * TILE_IMG)   // 32 MB
#define QSCALE (0.125f * 1.44269504088896340736f)  // 1/sqrt(64) * log2(e)

union Pfrag { unsigned u[4]; bf16x8 v; };

__device__ __forceinline__ unsigned pk2(float a, float b) {
  float2 t; t.x = a; t.y = b;
  __hip_bfloat162 hh = __float22bfloat162_rn(t);    // v_cvt_pk_bf16_f32
  union { __hip_bfloat162 h; unsigned u; } v; v.h = hh;
  return v.u;                                        // a lo16, b hi16
}
// native v_exp_f32 via builtin (hazards handled by compiler — R18 lesson)
#if defined(__has_builtin) && __has_builtin(__builtin_amdgcn_exp2f)
__device__ __forceinline__ float fast_exp2(float x) {
  return __builtin_amdgcn_exp2f(x);
}
#else
__device__ __forceinline__ float fast_exp2(float x) { return exp2f(x); }
#endif
__device__ __forceinline__ void pswap(unsigned &a, unsigned &b) {
  auto r = __builtin_amdgcn_permlane32_swap(a, b, false, false);
  a = r[0]; b = r[1];
}
#define SWZ(row,col) ((row)*128 + ((col) ^ ((((row) ^ ((row)>>2)) & 7) << 4)))

__device__ __forceinline__ void cp16(unsigned char* lds, const unsigned char* g) {
  __builtin_amdgcn_global_load_lds(
      (const __attribute__((address_space(1))) unsigned int*)g,
      (__attribute__((address_space(3))) unsigned int*)lds, 16, 0, 0);
}

// ---------------- prologue: build bf16 staged tile images in ws ----------------
__global__ __launch_bounds__(256) void fa_stage(
    const float* __restrict__ K, const float* __restrict__ V,
    unsigned char* __restrict__ img)
{
  const int tid = threadIdx.x;
  const int bid = blockIdx.x;
  const int bh  = bid >> 5;
  const int t0  = bid & 31;
  const int h = bh & (NH-1), b = bh >> 4;
  const size_t base = ((size_t)b * NL * NH + h) * NE + (size_t)(t0 * 64) * HE;
  unsigned char* kimg = img + (size_t)(bh * NKT + t0) * TILE_IMG;
  unsigned char* vimg = kimg + 8192;
  #pragma unroll
  for (int rep = 0; rep < 2; ++rep) {
    const int idx = rep * 256 + tid;
    const int row = idx >> 3, gr = idx & 7;
    const float* kp = K + base + (size_t)row * HE + gr * 8;
    f32x4 a0 = *(const f32x4*)kp;
    f32x4 a1 = *(const f32x4*)(kp + 4);
    Pfrag w;
    w.u[0] = pk2(a0[0], a0[1]); w.u[1] = pk2(a0[2], a0[3]);
    w.u[2] = pk2(a1[0], a1[1]); w.u[3] = pk2(a1[2], a1[3]);
    *(bf16x8*)(kimg + SWZ(row, gr * 16)) = w.v;
  }
  const int trow = tid >> 4, tcol = (tid & 15) * 4, sq = trow * 4;
  f32x4 vr[4];
  #pragma unroll
  for (int i = 0; i < 4; ++i)
    vr[i] = *(const f32x4*)(V + base + (size_t)(sq + i) * HE + tcol);
  #pragma unroll
  for (int j = 0; j < 4; ++j) {
    const int er = tcol + j;
    union { unsigned u[2]; bf16x4 v; } w;
    w.u[0] = pk2(vr[0][j], vr[1][j]);
    w.u[1] = pk2(vr[2][j], vr[3][j]);
    *(bf16x4*)(vimg + SWZ(er, sq * 2)) = w.v;
  }
}

// PACK: cvt_pk + pswap into PA0/PA1 (l is a VALU tree)
#define PACK(SC, PA0, PA1)                                                     \
      {                                                                        \
        unsigned c0 = pk2(SC[0],SC[1]),   c1 = pk2(SC[2],SC[3]);               \
        unsigned c2 = pk2(SC[4],SC[5]),   c3 = pk2(SC[6],SC[7]);               \
        unsigned c4 = pk2(SC[8],SC[9]),   c5 = pk2(SC[10],SC[11]);             \
        unsigned c6 = pk2(SC[12],SC[13]), c7 = pk2(SC[14],SC[15]);             \
        pswap(c0, c2);  pswap(c1, c3);                                         \
        pswap(c4, c6);  pswap(c5, c7);                                         \
        PA0.u[0]=c0; PA0.u[1]=c1; PA0.u[2]=c2; PA0.u[3]=c3;                    \
        PA1.u[0]=c4; PA1.u[1]=c5; PA1.u[2]=c6; PA1.u[3]=c7;                    \
      }

#define LSUM(SC)                                                               \
      l_run += ((((SC[0]+SC[1])+(SC[2]+SC[3]))+((SC[4]+SC[5])+(SC[6]+SC[7])))  \
             + (((SC[8]+SC[9])+(SC[10]+SC[11]))+((SC[12]+SC[13])+(SC[14]+SC[15]))));

#define SMPACK(SC, PA0, PA1)                                                   \
      _Pragma("unroll")                                                        \
      for (int r = 0; r < 16; ++r) SC[r] = fast_exp2(SC[r]);                   \
      LSUM(SC)                                                                 \
      PACK(SC, PA0, PA1)

// deferred PV for the PREVIOUS tile: register-only (p-frags x v-regs)
#define PVPREV()                                                               \
    {                                                                          \
      _Pragma("unroll")                                                        \
      for (int dt = 0; dt < 2; ++dt) {                                         \
        oacc[dt] = __builtin_amdgcn_mfma_f32_32x32x16_bf16(                    \
            vv[0][dt], p00.v, oacc[dt], 0, 0, 0);                              \
        oacc[dt] = __builtin_amdgcn_mfma_f32_32x32x16_bf16(                    \
            vv[2][dt], p10.v, oacc[dt], 0, 0, 0);                              \
        oacc[dt] = __builtin_amdgcn_mfma_f32_32x32x16_bf16(                    \
            vv[1][dt], p01.v, oacc[dt], 0, 0, 0);                              \
        oacc[dt] = __builtin_amdgcn_mfma_f32_32x32x16_bf16(                    \
            vv[3][dt], p11.v, oacc[dt], 0, 0, 0);                              \
      }                                                                        \
    }

// one kv64 step, 2-ring (tile IT in buf IT&1), 1-ahead prefetch:
//   wait(all) -> barrier -> prefetch IT+1 -> PV(IT-1) [regs] -> QK(IT)+softmax
//   -> vload V[IT] into regs (consumed next step)
#define STEP(IT, BUF)                                                          \
    {                                                                          \
      asm volatile("s_waitcnt vmcnt(0) lgkmcnt(0)" ::: "memory");              \
      __builtin_amdgcn_sched_barrier(0);                                       \
      __builtin_amdgcn_s_barrier();                                            \
      __builtin_amdgcn_sched_barrier(0);                                       \
      if ((IT) + 1 < nt) {                                                     \
        unsigned char* kd = &k_lds[(BUF)^1][0];                                \
        unsigned char* vd = &v_lds[(BUF)^1][0];                                \
        cp16(kd + wb,        src_pf);                                          \
        cp16(kd + 4096 + wb, src_pf + 4096);                                   \
        cp16(vd + wb,        src_pf + 8192);                                   \
        cp16(vd + 4096 + wb, src_pf + 12288);                                  \
        src_pf += TILE_IMG;                                                    \
      }                                                                        \
      if ((IT) > 0) PVPREV()                                                   \
      const unsigned char* kb = &k_lds[BUF][0];                                \
      const unsigned char* vbp = &v_lds[BUF][0];                               \
      const int kv0 = (IT)*64;                                                 \
      if (kv0 + 63 <= qb) {                                                    \
        f32x16 sc0 = (f32x16)0.0f, sc1 = (f32x16)0.0f;                         \
        _Pragma("unroll")                                                      \
        for (int ks = 0; ks < 4; ++ks) {                                       \
          bf16x8 af0 = *(const bf16x8*)(kb + addr4[ks]);                       \
          bf16x8 af1 = *(const bf16x8*)(kb + addr4[ks] + 4096);                \
          sc0 = __builtin_amdgcn_mfma_f32_32x32x16_bf16(af0, qf[ks], sc0,0,0,0);\
          sc1 = __builtin_amdgcn_mfma_f32_32x32x16_bf16(af1, qf[ks], sc1,0,0,0);\
        }                                                                      \
        SMPACK(sc0, p00, p01)                                                  \
        SMPACK(sc1, p10, p11)                                                  \
      } else {                                                                 \
        if (kv0 <= qb + 31) {                                                  \
          f32x16 sc = (f32x16)0.0f;                                            \
          _Pragma("unroll")                                                    \
          for (int ks = 0; ks < 4; ++ks) {                                     \
            bf16x8 af = *(const bf16x8*)(kb + addr4[ks]);                      \
            sc = __builtin_amdgcn_mfma_f32_32x32x16_bf16(af, qf[ks], sc,0,0,0);\
          }                                                                    \
          _Pragma("unroll")                                                    \
          for (int r = 0; r < 16; ++r) {                                       \
            const int kvg = kv0 + (r&3) + 8*(r>>2) + 4*hi;                     \
            sc[r] = (kvg > qg) ? 0.0f : fast_exp2(sc[r]);                      \
          }                                                                    \
          LSUM(sc)                                                             \
          PACK(sc, p00, p01)                                                   \
        } else {                                                               \
          p00.u[0]=0; p00.u[1]=0; p00.u[2]=0; p00.u[3]=0; p01 = p00;           \
        }                                                                      \
        if (kv0 + 32 <= qb + 31) {                                             \
          f32x16 sc = (f32x16)0.0f;                                            \
          _Pragma("unroll")                                                    \
          for (int ks = 0; ks < 4; ++ks) {                                     \
            bf16x8 af = *(const bf16x8*)(kb + addr4[ks] + 4096);               \
            sc = __builtin_amdgcn_mfma_f32_32x32x16_bf16(af, qf[ks], sc,0,0,0);\
          }                                                                    \
          _Pragma("unroll")                                                    \
          for (int r = 0; r < 16; ++r) {                                       \
            const int kvg = kv0 + 32 + (r&3) + 8*(r>>2) + 4*hi;                \
            sc[r] = (kvg > qg) ? 0.0f : fast_exp2(sc[r]);                      \
          }                                                                    \
          LSUM(sc)                                                             \
          PACK(sc, p10, p11)                                                   \
        } else {                                                               \
          p10.u[0]=0; p10.u[1]=0; p10.u[2]=0; p10.u[3]=0; p11 = p10;           \
        }                                                                      \
      }                                                                        \
      _Pragma("unroll")                                                        \
      for (int j = 0; j < 4; ++j) {                                            \
        vv[j][0] = *(const bf16x8*)(vbp + addr4[j]);                           \
        vv[j][1] = *(const bf16x8*)(vbp + addr4[j] + 4096);                    \
      }                                                                        \
    }

// ---------------- main: 2-ring, 1024 LPT blocks, 4 blk/CU, reg-PV ----------------
__global__ __launch_bounds__(256, 4) void fa_fwd(
    const float* __restrict__ Q, const unsigned char* __restrict__ img,
    float* __restrict__ O)
{
  __shared__ unsigned char k_lds[2][8192];   // 2-ring = 32KB total
  __shared__ unsigned char v_lds[2][8192];

  const int tid  = threadIdx.x;
  const int lane = tid & 63;
  const int wid  = tid >> 6;
  const int hi   = lane >> 5;
  const int ln   = lane & 31;

  // LPT: longest q-tiles first; bid%8 == bh%8 keeps a (b,h)'s 16 blocks
  // on one XCD for K/V image L2 reuse.
  const int bid = blockIdx.x;
  const int bh  = bid & 63;
  const int qt  = (NQT - 1) - (bid >> 6);
  const int h   = bh & (NH-1);
  const int b   = bh >> 4;

  const size_t base = ((size_t)b * NL * NH + h) * NE;
  const float* Qb = Q + base;
  float*       Ob = O + base;
  const unsigned char* bimg = img + (size_t)bh * NKT * TILE_IMG;

  int addr4[4];
  {
    const int F = ((ln ^ (ln >> 2)) & 7) << 4;
    #pragma unroll
    for (int j = 0; j < 4; ++j) addr4[j] = ln*128 + ((j*32 + hi*16) ^ F);
  }
  const int wb = wid << 10;

  const int q0 = qt * QBLK;
  const int qb = q0 + wid * QW;
  const int nt = qt * 2 + 2;                     // even
  const int qg = qb + ln;

  // ---- Q fragments ----
  bf16x8 qf[4];
  {
    const float* qp = Qb + (size_t)(qb + ln) * HE + hi * 8;
    #pragma unroll
    for (int ks = 0; ks < 4; ++ks) {
      f32x4 a0 = *(const f32x4*)(qp + ks*16);
      f32x4 a1 = *(const f32x4*)(qp + ks*16 + 4);
      Pfrag f;
      f.u[0] = pk2(a0[0]*QSCALE, a0[1]*QSCALE);
      f.u[1] = pk2(a0[2]*QSCALE, a0[3]*QSCALE);
      f.u[2] = pk2(a1[0]*QSCALE, a1[1]*QSCALE);
      f.u[3] = pk2(a1[2]*QSCALE, a1[3]*QSCALE);
      qf[ks] = f.v;
    }
  }
  f32x16 oacc[2];
  oacc[0] = (f32x16)0.0f; oacc[1] = (f32x16)0.0f;
  float l_run = 0.0f;
  Pfrag p00, p01, p10, p11;       // deferred P frags (prev tile)
  p00.u[0]=0;p00.u[1]=0;p00.u[2]=0;p00.u[3]=0; p01=p00; p10=p00; p11=p00;
  bf16x8 vv[4][2];                // prev tile's V frags in registers

  // preload tile 0 into buf0 (1-ahead pipeline)
  asm volatile("s_waitcnt vmcnt(0)" ::: "memory");
  __builtin_amdgcn_sched_barrier(0);
  const unsigned char* src_pf = bimg + (size_t)tid * 16;
  cp16(&k_lds[0][0] + wb,        src_pf);
  cp16(&k_lds[0][0] + 4096 + wb, src_pf + 4096);
  cp16(&v_lds[0][0] + wb,        src_pf + 8192);
  cp16(&v_lds[0][0] + 4096 + wb, src_pf + 12288);
  src_pf += TILE_IMG;

  int it0 = 0;
  #pragma unroll 1
  for (; it0 + 2 <= nt; it0 += 2) {   // nt always even
    STEP(it0 + 0, 0)
    STEP(it0 + 1, 1)
  }
  PVPREV()   // flush deferred PV for tile nt-1

  const float l_tot = l_run + __shfl_xor(l_run, 32);
  const float inv = 1.0f / l_tot;
  float* op = Ob + (size_t)(qb + ln) * HE;
  #pragma unroll
  for (int dt = 0; dt < 2; ++dt)
    #pragma unroll
    for (int rq = 0; rq < 4; ++rq) {
      f32x4 w;
      w[0]=oacc[dt][rq*4+0]*inv; w[1]=oacc[dt][rq*4+1]*inv;
      w[2]=oacc[dt][rq*4+2]*inv; w[3]=oacc[dt][rq*4+3]*inv;
      *(f32x4*)(op + dt*32 + 8*rq + 4*hi) = w;
    }
}

// ---------------- fused fallback (R6-style) if ws too small ----------------
__global__ __launch_bounds__(256, 3) void fa_fwd_fused(
    const float* __restrict__ Q, const float* __restrict__ K,
    const float* __restrict__ V, float* __restrict__ O)
{
  __shared__ unsigned char kf_lds[2][64*128];
  __shared__ unsigned char vf_lds[2][64*128];
  const int tid  = threadIdx.x;
  const int lane = tid & 63;
  const int wid  = tid >> 6;
  const int hi   = lane >> 5;
  const int ln   = lane & 31;
  const int trow = tid >> 4;
  const int tcol = (tid & 15) * 4;
  const int sq   = trow * 4;
  const int bidp = blockIdx.x;
  const int lb   = (bidp & 7) * 64 + (bidp >> 3);
  const int pair = lb & 7;
  const int bh   = lb >> 3;
  const int h    = bh & (NH-1);
  const int b    = bh >> 4;
  const size_t base = ((size_t)b * NL * NH + h) * NE;
  const float* Qb = Q + base;
  const float* Kb = K + base;
  const float* Vb = V + base;
  float*       Ob = O + base;
  int cur = 0;
  #pragma unroll 1
  for (int hf = 0; hf < 2; ++hf) {
    const int qt = hf ? (NQT - 1 - pair) : pair;
    const int q0 = qt * QBLK;
    const int qb = q0 + wid * QW;
    const int nt = qt * 2 + 2;
    const int qg = qb + ln;
    bf16x8 qf[4];
    {
      const float* qp = Qb + (size_t)(qb + ln) * HE + hi * 8;
      #pragma unroll
      for (int ks = 0; ks < 4; ++ks) {
        f32x4 a0 = *(const f32x4*)(qp + ks*16);
        f32x4 a1 = *(const f32x4*)(qp + ks*16 + 4);
        Pfrag f;
        f.u[0] = pk2(a0[0]*QSCALE, a0[1]*QSCALE);
        f.u[1] = pk2(a0[2]*QSCALE, a0[3]*QSCALE);
        f.u[2] = pk2(a1[0]*QSCALE, a1[1]*QSCALE);
        f.u[3] = pk2(a1[2]*QSCALE, a1[3]*QSCALE);
        qf[ks] = f.v;
      }
    }
    f32x16 oacc[2];
    oacc[0] = (f32x16)0.0f; oacc[1] = (f32x16)0.0f;
    float l_run = 0.0f;
    f32x4 kreg[4], vreg[4];
    #pragma unroll
    for (int p = 0; p < 4; ++p)
      kreg[p] = *(const f32x4*)(Kb + (size_t)(trow + p*16) * HE + tcol);
    #pragma unroll
    for (int i = 0; i < 4; ++i)
      vreg[i] = *(const f32x4*)(Vb + (size_t)(sq + i) * HE + tcol);
    #pragma unroll 1
    for (int it = 0; it < nt; ++it) {
      unsigned char* kb = kf_lds[cur];
      unsigned char* vb = vf_lds[cur];
      #pragma unroll
      for (int p = 0; p < 4; ++p) {
        const int row = trow + p*16;
        union { unsigned u[2]; bf16x4 v; } w;
        w.u[0] = pk2(kreg[p][0], kreg[p][1]);
        w.u[1] = pk2(kreg[p][2], kreg[p][3]);
        *(bf16x4*)(kb + SWZ(row, tcol*2)) = w.v;
      }
      #pragma unroll
      for (int j = 0; j < 4; ++j) {
        const int er = tcol + j;
        union { unsigned u[2]; bf16x4 v; } w;
        w.u[0] = pk2(vreg[0][j], vreg[1][j]);
        w.u[1] = pk2(vreg[2][j], vreg[3][j]);
        *(bf16x4*)(vb + SWZ(er, sq*2)) = w.v;
      }
      if (it + 1 < nt) {
        const int s0 = (it + 1) * 64;
        #pragma unroll
        for (int p = 0; p < 4; ++p)
          kreg[p] = *(const f32x4*)(Kb + (size_t)(s0 + trow + p*16) * HE + tcol);
        #pragma unroll
        for (int i = 0; i < 4; ++i)
          vreg[i] = *(const f32x4*)(Vb + (size_t)(s0 + sq + i) * HE + tcol);
      }
      asm volatile("s_waitcnt lgkmcnt(0)" ::: "memory");
      __builtin_amdgcn_sched_barrier(0);
      __builtin_amdgcn_s_barrier();
      __builtin_amdgcn_sched_barrier(0);
      #pragma unroll
      for (int sub = 0; sub < 2; ++sub) {
        const int kv0s = it*64 + sub*32;
        if (kv0s <= qb + QW - 1) {
          f32x16 sc = (f32x16)0.0f;
          #pragma unroll
          for (int ks = 0; ks < 4; ++ks) {
            const int kvr = sub*32 + ln;
            bf16x8 af = *(const bf16x8*)(kb + SWZ(kvr, ks*32 + hi*16));
            sc = __builtin_amdgcn_mfma_f32_32x32x16_bf16(af, qf[ks], sc, 0, 0, 0);
          }
          if (kv0s + 31 > qb) {
            #pragma unroll
            for (int r = 0; r < 16; ++r) {
              const int kvg = kv0s + (r&3) + 8*(r>>2) + 4*hi;
              sc[r] = (kvg > qg) ? 0.0f : fast_exp2(sc[r]);
            }
          } else {
            #pragma unroll
            for (int r = 0; r < 16; ++r) sc[r] = fast_exp2(sc[r]);
          }
          float s0_ = (sc[0]+sc[1])+(sc[2]+sc[3]);
          float s1_ = (sc[4]+sc[5])+(sc[6]+sc[7]);
          float s2_ = (sc[8]+sc[9])+(sc[10]+sc[11]);
          float s3_ = (sc[12]+sc[13])+(sc[14]+sc[15]);
          float ls = (s0_+s1_)+(s2_+s3_);
          ls += __shfl_xor(ls, 32);
          l_run += ls;
          unsigned c0 = pk2(sc[0],sc[1]),   c1 = pk2(sc[2],sc[3]);
          unsigned c2 = pk2(sc[4],sc[5]),   c3 = pk2(sc[6],sc[7]);
          unsigned c4 = pk2(sc[8],sc[9]),   c5 = pk2(sc[10],sc[11]);
          unsigned c6 = pk2(sc[12],sc[13]), c7 = pk2(sc[14],sc[15]);
          pswap(c0, c2);  pswap(c1, c3);
          pswap(c4, c6);  pswap(c5, c7);
          Pfrag pa0, pa1;
          pa0.u[0]=c0; pa0.u[1]=c1; pa0.u[2]=c2; pa0.u[3]=c3;
          pa1.u[0]=c4; pa1.u[1]=c5; pa1.u[2]=c6; pa1.u[3]=c7;
          #pragma unroll
          for (int dt = 0; dt < 2; ++dt) {
            const int dr = dt*32 + ln;
            #pragma unroll
            for (int ks2 = 0; ks2 < 2; ++ks2) {
              bf16x8 av = *(const bf16x8*)(vb + SWZ(dr, sub*64 + ks2*32 + hi*16));
              oacc[dt] = __builtin_amdgcn_mfma_f32_32x32x16_bf16(
                  av, ks2 ? pa1.v : pa0.v, oacc[dt], 0, 0, 0);
            }
          }
        }
      }
      cur ^= 1;
    }
    const float inv = 1.0f / l_run;
    float* op = Ob + (size_t)(qb + ln) * HE;
    #pragma unroll
    for (int dt = 0; dt < 2; ++dt)
      #pragma unroll
      for (int rq = 0; rq < 4; ++rq) {
        f32x4 w;
        w[0]=oacc[dt][rq*4+0]*inv; w[1]=oacc[dt][rq*4+1]*inv;
        w[2]=oacc[dt][rq*4+2]*inv; w[3]=oacc[dt][rq*4+3]*inv;
        *(f32x4*)(op + dt*32 + 8*rq + 4*hi) = w;
      }
  }
}

extern "C" void kernel_launch(void* const* d_in, const int* in_sizes, int n_in,
                              void* d_out, int out_size, void* d_ws, size_t ws_size,
                              hipStream_t stream) {
  const float* Q = (const float*)d_in[0];
  const float* K = (const float*)d_in[1];
  const float* V = (const float*)d_in[2];
  float* O = (float*)d_out;
  if (ws_size >= WS_NEED) {
    fa_stage<<<dim3(NBH * NKT), dim3(256), 0, stream>>>(K, V, (unsigned char*)d_ws);
    fa_fwd<<<dim3(NBH * NQT), dim3(256), 0, stream>>>(   // 1024 blocks, LPT
        Q, (const unsigned char*)d_ws, O);
  } else {
    fa_fwd_fused<<<dim3(NB * NH * 8), dim3(256), 0, stream>>>(Q, K, V, O);
  }
}

// Round 24
// 72.990 us; speedup vs baseline: 2.1130x; 2.1130x over previous
//
#include <hip/hip_runtime.h>
#include <hip/hip_bf16.h>

typedef __attribute__((ext_vector_type(8))) short bf16x8;
typedef __attribute__((ext_vector_type(4))) short bf16x4;
typedef __attribute__((ext_vector_type(4))) float f32x4;
typedef __attribute__((ext_vector_type(16))) float f32x16;

#define NB 4
#define NL 2048
#define NH 16
#define NE 64
#define HE (NH*NE)
#define QW 32
#define QBLK 128
#define NQT (NL/QBLK)      // 16
#define NBH 64
#define NKT 32             // kv64 tiles per (b,h)
#define TILE_IMG 16384     // 8KB K + 8KB V^T per (bh, kv-tile)
#define WS_NEED ((size_t)NBH * NKT * TILE_IMG)   // 32 MB
#define QSCALE (0.125f * 1.44269504088896340736f)  // 1/sqrt(64) * log2(e)

union Pfrag { unsigned u[4]; bf16x8 v; };

__device__ __forceinline__ unsigned pk2(float a, float b) {
  float2 t; t.x = a; t.y = b;
  __hip_bfloat162 hh = __float22bfloat162_rn(t);    // v_cvt_pk_bf16_f32
  union { __hip_bfloat162 h; unsigned u; } v; v.h = hh;
  return v.u;                                        // a lo16, b hi16
}
// native v_exp_f32 via builtin (hazards handled by compiler — R18 lesson)
#if defined(__has_builtin) && __has_builtin(__builtin_amdgcn_exp2f)
__device__ __forceinline__ float fast_exp2(float x) {
  return __builtin_amdgcn_exp2f(x);
}
#else
__device__ __forceinline__ float fast_exp2(float x) { return exp2f(x); }
#endif
__device__ __forceinline__ void pswap(unsigned &a, unsigned &b) {
  auto r = __builtin_amdgcn_permlane32_swap(a, b, false, false);
  a = r[0]; b = r[1];
}
#define SWZ(row,col) ((row)*128 + ((col) ^ ((((row) ^ ((row)>>2)) & 7) << 4)))

__device__ __forceinline__ void cp16(unsigned char* lds, const unsigned char* g) {
  __builtin_amdgcn_global_load_lds(
      (const __attribute__((address_space(1))) unsigned int*)g,
      (__attribute__((address_space(3))) unsigned int*)lds, 16, 0, 0);
}

// ---------------- prologue: build bf16 staged tile images in ws ----------------
__global__ __launch_bounds__(256) void fa_stage(
    const float* __restrict__ K, const float* __restrict__ V,
    unsigned char* __restrict__ img)
{
  const int tid = threadIdx.x;
  const int bid = blockIdx.x;
  const int bh  = bid >> 5;
  const int t0  = bid & 31;
  const int h = bh & (NH-1), b = bh >> 4;
  const size_t base = ((size_t)b * NL * NH + h) * NE + (size_t)(t0 * 64) * HE;
  unsigned char* kimg = img + (size_t)(bh * NKT + t0) * TILE_IMG;
  unsigned char* vimg = kimg + 8192;
  #pragma unroll
  for (int rep = 0; rep < 2; ++rep) {
    const int idx = rep * 256 + tid;
    const int row = idx >> 3, gr = idx & 7;
    const float* kp = K + base + (size_t)row * HE + gr * 8;
    f32x4 a0 = *(const f32x4*)kp;
    f32x4 a1 = *(const f32x4*)(kp + 4);
    Pfrag w;
    w.u[0] = pk2(a0[0], a0[1]); w.u[1] = pk2(a0[2], a0[3]);
    w.u[2] = pk2(a1[0], a1[1]); w.u[3] = pk2(a1[2], a1[3]);
    *(bf16x8*)(kimg + SWZ(row, gr * 16)) = w.v;
  }
  const int trow = tid >> 4, tcol = (tid & 15) * 4, sq = trow * 4;
  f32x4 vr[4];
  #pragma unroll
  for (int i = 0; i < 4; ++i)
    vr[i] = *(const f32x4*)(V + base + (size_t)(sq + i) * HE + tcol);
  #pragma unroll
  for (int j = 0; j < 4; ++j) {
    const int er = tcol + j;
    union { unsigned u[2]; bf16x4 v; } w;
    w.u[0] = pk2(vr[0][j], vr[1][j]);
    w.u[1] = pk2(vr[2][j], vr[3][j]);
    *(bf16x4*)(vimg + SWZ(er, sq * 2)) = w.v;
  }
}

// PACK: cvt_pk + pswap into PA0/PA1 (l is a VALU tree)
#define PACK(SC, PA0, PA1)                                                     \
      {                                                                        \
        unsigned c0 = pk2(SC[0],SC[1]),   c1 = pk2(SC[2],SC[3]);               \
        unsigned c2 = pk2(SC[4],SC[5]),   c3 = pk2(SC[6],SC[7]);               \
        unsigned c4 = pk2(SC[8],SC[9]),   c5 = pk2(SC[10],SC[11]);             \
        unsigned c6 = pk2(SC[12],SC[13]), c7 = pk2(SC[14],SC[15]);             \
        pswap(c0, c2);  pswap(c1, c3);                                         \
        pswap(c4, c6);  pswap(c5, c7);                                         \
        PA0.u[0]=c0; PA0.u[1]=c1; PA0.u[2]=c2; PA0.u[3]=c3;                    \
        PA1.u[0]=c4; PA1.u[1]=c5; PA1.u[2]=c6; PA1.u[3]=c7;                    \
      }

#define LSUM(SC)                                                               \
      l_run += ((((SC[0]+SC[1])+(SC[2]+SC[3]))+((SC[4]+SC[5])+(SC[6]+SC[7])))  \
             + (((SC[8]+SC[9])+(SC[10]+SC[11]))+((SC[12]+SC[13])+(SC[14]+SC[15]))));

#define SMPACK(SC, PA0, PA1)                                                   \
      _Pragma("unroll")                                                        \
      for (int r = 0; r < 16; ++r) SC[r] = fast_exp2(SC[r]);                   \
      LSUM(SC)                                                                 \
      PACK(SC, PA0, PA1)

// deferred PV for the PREVIOUS tile: register-only (p-frags x vv-regs)
#define PVPREV()                                                               \
    {                                                                          \
      _Pragma("unroll")                                                        \
      for (int dt = 0; dt < 2; ++dt) {                                         \
        oacc[dt] = __builtin_amdgcn_mfma_f32_32x32x16_bf16(                    \
            vv[0][dt], p00.v, oacc[dt], 0, 0, 0);                              \
        oacc[dt] = __builtin_amdgcn_mfma_f32_32x32x16_bf16(                    \
            vv[2][dt], p10.v, oacc[dt], 0, 0, 0);                              \
        oacc[dt] = __builtin_amdgcn_mfma_f32_32x32x16_bf16(                    \
            vv[1][dt], p01.v, oacc[dt], 0, 0, 0);                              \
        oacc[dt] = __builtin_amdgcn_mfma_f32_32x32x16_bf16(                    \
            vv[3][dt], p11.v, oacc[dt], 0, 0, 0);                              \
      }                                                                        \
    }

// one tile's compute (no barrier/wait): PV(prev) [regs] -> QK+SM -> p-frags
// -> vload V[IT] into vv regs (consumed next tile)
#define TILE(IT, BUF)                                                          \
    {                                                                          \
      if ((IT) > 0) PVPREV()                                                   \
      const unsigned char* kb = &k_lds[BUF][0];                                \
      const unsigned char* vbp = &v_lds[BUF][0];                               \
      const int kv0 = (IT)*64;                                                 \
      if (kv0 + 63 <= qb) {                                                    \
        f32x16 sc0 = (f32x16)0.0f, sc1 = (f32x16)0.0f;                         \
        _Pragma("unroll")                                                      \
        for (int ks = 0; ks < 4; ++ks) {                                       \
          bf16x8 af0 = *(const bf16x8*)(kb + addr4[ks]);                       \
          bf16x8 af1 = *(const bf16x8*)(kb + addr4[ks] + 4096);                \
          sc0 = __builtin_amdgcn_mfma_f32_32x32x16_bf16(af0, qf[ks], sc0,0,0,0);\
          sc1 = __builtin_amdgcn_mfma_f32_32x32x16_bf16(af1, qf[ks], sc1,0,0,0);\
        }                                                                      \
        SMPACK(sc0, p00, p01)                                                  \
        SMPACK(sc1, p10, p11)                                                  \
      } else {                                                                 \
        if (kv0 <= qb + 31) {                                                  \
          f32x16 sc = (f32x16)0.0f;                                            \
          _Pragma("unroll")                                                    \
          for (int ks = 0; ks < 4; ++ks) {                                     \
            bf16x8 af = *(const bf16x8*)(kb + addr4[ks]);                      \
            sc = __builtin_amdgcn_mfma_f32_32x32x16_bf16(af, qf[ks], sc,0,0,0);\
          }                                                                    \
          _Pragma("unroll")                                                    \
          for (int r = 0; r < 16; ++r) {                                       \
            const int kvg = kv0 + (r&3) + 8*(r>>2) + 4*hi;                     \
            sc[r] = (kvg > qg) ? 0.0f : fast_exp2(sc[r]);                      \
          }                                                                    \
          LSUM(sc)                                                             \
          PACK(sc, p00, p01)                                                   \
        } else {                                                               \
          p00.u[0]=0; p00.u[1]=0; p00.u[2]=0; p00.u[3]=0; p01 = p00;           \
        }                                                                      \
        if (kv0 + 32 <= qb + 31) {                                             \
          f32x16 sc = (f32x16)0.0f;                                            \
          _Pragma("unroll")                                                    \
          for (int ks = 0; ks < 4; ++ks) {                                     \
            bf16x8 af = *(const bf16x8*)(kb + addr4[ks] + 4096);               \
            sc = __builtin_amdgcn_mfma_f32_32x32x16_bf16(af, qf[ks], sc,0,0,0);\
          }                                                                    \
          _Pragma("unroll")                                                    \
          for (int r = 0; r < 16; ++r) {                                       \
            const int kvg = kv0 + 32 + (r&3) + 8*(r>>2) + 4*hi;                \
            sc[r] = (kvg > qg) ? 0.0f : fast_exp2(sc[r]);                      \
          }                                                                    \
          LSUM(sc)                                                             \
          PACK(sc, p10, p11)                                                   \
        } else {                                                               \
          p10.u[0]=0; p10.u[1]=0; p10.u[2]=0; p10.u[3]=0; p11 = p10;           \
        }                                                                      \
      }                                                                        \
      _Pragma("unroll")                                                        \
      for (int j = 0; j < 4; ++j) {                                            \
        vv[j][0] = *(const bf16x8*)(vbp + addr4[j]);                           \
        vv[j][1] = *(const bf16x8*)(vbp + addr4[j] + 4096);                    \
      }                                                                        \
    }

// superstep: ONE barrier covers TWO tiles T,T+1 (bufs B0,B1); prefetches
// tiles T+2,T+3 into bufs B0^2,B1^2 (disjoint from all readers this superstep)
#define SUPER(T, B0, B1)                                                       \
    {                                                                          \
      asm volatile("s_waitcnt vmcnt(0) lgkmcnt(0)" ::: "memory");              \
      __builtin_amdgcn_sched_barrier(0);                                       \
      __builtin_amdgcn_s_barrier();                                            \
      __builtin_amdgcn_sched_barrier(0);                                       \
      if ((T) + 2 < nt) {                                                      \
        unsigned char* kd = &k_lds[(B0)^2][0];                                 \
        unsigned char* vd = &v_lds[(B0)^2][0];                                 \
        cp16(kd + wb,        src_pf);                                          \
        cp16(kd + 4096 + wb, src_pf + 4096);                                   \
        cp16(vd + wb,        src_pf + 8192);                                   \
        cp16(vd + 4096 + wb, src_pf + 12288);                                  \
        src_pf += TILE_IMG;                                                    \
        if ((T) + 3 < nt) {                                                    \
          unsigned char* kd2 = &k_lds[(B1)^2][0];                              \
          unsigned char* vd2 = &v_lds[(B1)^2][0];                              \
          cp16(kd2 + wb,        src_pf);                                       \
          cp16(kd2 + 4096 + wb, src_pf + 4096);                                \
          cp16(vd2 + wb,        src_pf + 8192);                                \
          cp16(vd2 + 4096 + wb, src_pf + 12288);                               \
          src_pf += TILE_IMG;                                                  \
        }                                                                      \
      }                                                                        \
      TILE((T) + 0, B0)                                                        \
      TILE((T) + 1, B1)                                                        \
    }

// ---------------- main: 4-ring, 2-tile supersteps, 1024 LPT blocks ----------------
__global__ __launch_bounds__(256, 2) void fa_fwd(
    const float* __restrict__ Q, const unsigned char* __restrict__ img,
    float* __restrict__ O)
{
  __shared__ unsigned char k_lds[4][8192];   // 4-buffer ring = 64KB total
  __shared__ unsigned char v_lds[4][8192];

  const int tid  = threadIdx.x;
  const int lane = tid & 63;
  const int wid  = tid >> 6;
  const int hi   = lane >> 5;
  const int ln   = lane & 31;

  // LPT: longest q-tiles first; bid%8 == bh%8 keeps a (b,h)'s 16 blocks
  // on one XCD for K/V image L2 reuse.
  const int bid = blockIdx.x;
  const int bh  = bid & 63;
  const int qt  = (NQT - 1) - (bid >> 6);
  const int h   = bh & (NH-1);
  const int b   = bh >> 4;

  const size_t base = ((size_t)b * NL * NH + h) * NE;
  const float* Qb = Q + base;
  float*       Ob = O + base;
  const unsigned char* bimg = img + (size_t)bh * NKT * TILE_IMG;

  int addr4[4];
  {
    const int F = ((ln ^ (ln >> 2)) & 7) << 4;
    #pragma unroll
    for (int j = 0; j < 4; ++j) addr4[j] = ln*128 + ((j*32 + hi*16) ^ F);
  }
  const int wb = wid << 10;

  const int q0 = qt * QBLK;
  const int qb = q0 + wid * QW;
  const int nt = qt * 2 + 2;                     // even; nt%4 in {0,2}
  const int qg = qb + ln;

  // ---- Q fragments ----
  bf16x8 qf[4];
  {
    const float* qp = Qb + (size_t)(qb + ln) * HE + hi * 8;
    #pragma unroll
    for (int ks = 0; ks < 4; ++ks) {
      f32x4 a0 = *(const f32x4*)(qp + ks*16);
      f32x4 a1 = *(const f32x4*)(qp + ks*16 + 4);
      Pfrag f;
      f.u[0] = pk2(a0[0]*QSCALE, a0[1]*QSCALE);
      f.u[1] = pk2(a0[2]*QSCALE, a0[3]*QSCALE);
      f.u[2] = pk2(a1[0]*QSCALE, a1[1]*QSCALE);
      f.u[3] = pk2(a1[2]*QSCALE, a1[3]*QSCALE);
      qf[ks] = f.v;
    }
  }
  f32x16 oacc[2];
  oacc[0] = (f32x16)0.0f; oacc[1] = (f32x16)0.0f;
  float l_run = 0.0f;
  Pfrag p00, p01, p10, p11;       // deferred P frags (prev tile)
  p00.u[0]=0;p00.u[1]=0;p00.u[2]=0;p00.u[3]=0; p01=p00; p10=p00; p11=p00;
  bf16x8 vv[4][2];                // prev tile's V frags in registers

  // preload tiles 0,1 into bufs 0,1
  asm volatile("s_waitcnt vmcnt(0)" ::: "memory");
  __builtin_amdgcn_sched_barrier(0);
  const unsigned char* src_pf = bimg + (size_t)tid * 16;
  cp16(&k_lds[0][0] + wb,        src_pf);
  cp16(&k_lds[0][0] + 4096 + wb, src_pf + 4096);
  cp16(&v_lds[0][0] + wb,        src_pf + 8192);
  cp16(&v_lds[0][0] + 4096 + wb, src_pf + 12288);
  src_pf += TILE_IMG;
  cp16(&k_lds[1][0] + wb,        src_pf);
  cp16(&k_lds[1][0] + 4096 + wb, src_pf + 4096);
  cp16(&v_lds[1][0] + wb,        src_pf + 8192);
  cp16(&v_lds[1][0] + 4096 + wb, src_pf + 12288);
  src_pf += TILE_IMG;

  int t0 = 0;
  #pragma unroll 1
  for (; t0 + 4 <= nt; t0 += 4) {
    SUPER(t0 + 0, 0, 1)
    SUPER(t0 + 2, 2, 3)
  }
  if (t0 < nt) SUPER(t0, 0, 1)     // nt%4==2 tail (bufs 0,1: t0%4==0)
  PVPREV()   // flush deferred PV for tile nt-1

  const float l_tot = l_run + __shfl_xor(l_run, 32);
  const float inv = 1.0f / l_tot;
  float* op = Ob + (size_t)(qb + ln) * HE;
  #pragma unroll
  for (int dt = 0; dt < 2; ++dt)
    #pragma unroll
    for (int rq = 0; rq < 4; ++rq) {
      f32x4 w;
      w[0]=oacc[dt][rq*4+0]*inv; w[1]=oacc[dt][rq*4+1]*inv;
      w[2]=oacc[dt][rq*4+2]*inv; w[3]=oacc[dt][rq*4+3]*inv;
      *(f32x4*)(op + dt*32 + 8*rq + 4*hi) = w;
    }
}

// ---------------- fused fallback (R6-style) if ws too small ----------------
__global__ __launch_bounds__(256, 3) void fa_fwd_fused(
    const float* __restrict__ Q, const float* __restrict__ K,
    const float* __restrict__ V, float* __restrict__ O)
{
  __shared__ unsigned char kf_lds[2][64*128];
  __shared__ unsigned char vf_lds[2][64*128];
  const int tid  = threadIdx.x;
  const int lane = tid & 63;
  const int wid  = tid >> 6;
  const int hi   = lane >> 5;
  const int ln   = lane & 31;
  const int trow = tid >> 4;
  const int tcol = (tid & 15) * 4;
  const int sq   = trow * 4;
  const int bidp = blockIdx.x;
  const int lb   = (bidp & 7) * 64 + (bidp >> 3);
  const int pair = lb & 7;
  const int bh   = lb >> 3;
  const int h    = bh & (NH-1);
  const int b    = bh >> 4;
  const size_t base = ((size_t)b * NL * NH + h) * NE;
  const float* Qb = Q + base;
  const float* Kb = K + base;
  const float* Vb = V + base;
  float*       Ob = O + base;
  int cur = 0;
  #pragma unroll 1
  for (int hf = 0; hf < 2; ++hf) {
    const int qt = hf ? (NQT - 1 - pair) : pair;
    const int q0 = qt * QBLK;
    const int qb = q0 + wid * QW;
    const int nt = qt * 2 + 2;
    const int qg = qb + ln;
    bf16x8 qf[4];
    {
      const float* qp = Qb + (size_t)(qb + ln) * HE + hi * 8;
      #pragma unroll
      for (int ks = 0; ks < 4; ++ks) {
        f32x4 a0 = *(const f32x4*)(qp + ks*16);
        f32x4 a1 = *(const f32x4*)(qp + ks*16 + 4);
        Pfrag f;
        f.u[0] = pk2(a0[0]*QSCALE, a0[1]*QSCALE);
        f.u[1] = pk2(a0[2]*QSCALE, a0[3]*QSCALE);
        f.u[2] = pk2(a1[0]*QSCALE, a1[1]*QSCALE);
        f.u[3] = pk2(a1[2]*QSCALE, a1[3]*QSCALE);
        qf[ks] = f.v;
      }
    }
    f32x16 oacc[2];
    oacc[0] = (f32x16)0.0f; oacc[1] = (f32x16)0.0f;
    float l_run = 0.0f;
    f32x4 kreg[4], vreg[4];
    #pragma unroll
    for (int p = 0; p < 4; ++p)
      kreg[p] = *(const f32x4*)(Kb + (size_t)(trow + p*16) * HE + tcol);
    #pragma unroll
    for (int i = 0; i < 4; ++i)
      vreg[i] = *(const f32x4*)(Vb + (size_t)(sq + i) * HE + tcol);
    #pragma unroll 1
    for (int it = 0; it < nt; ++it) {
      unsigned char* kb = kf_lds[cur];
      unsigned char* vb = vf_lds[cur];
      #pragma unroll
      for (int p = 0; p < 4; ++p) {
        const int row = trow + p*16;
        union { unsigned u[2]; bf16x4 v; } w;
        w.u[0] = pk2(kreg[p][0], kreg[p][1]);
        w.u[1] = pk2(kreg[p][2], kreg[p][3]);
        *(bf16x4*)(kb + SWZ(row, tcol*2)) = w.v;
      }
      #pragma unroll
      for (int j = 0; j < 4; ++j) {
        const int er = tcol + j;
        union { unsigned u[2]; bf16x4 v; } w;
        w.u[0] = pk2(vreg[0][j], vreg[1][j]);
        w.u[1] = pk2(vreg[2][j], vreg[3][j]);
        *(bf16x4*)(vb + SWZ(er, sq*2)) = w.v;
      }
      if (it + 1 < nt) {
        const int s0 = (it + 1) * 64;
        #pragma unroll
        for (int p = 0; p < 4; ++p)
          kreg[p] = *(const f32x4*)(Kb + (size_t)(s0 + trow + p*16) * HE + tcol);
        #pragma unroll
        for (int i = 0; i < 4; ++i)
          vreg[i] = *(const f32x4*)(Vb + (size_t)(s0 + sq + i) * HE + tcol);
      }
      asm volatile("s_waitcnt lgkmcnt(0)" ::: "memory");
      __builtin_amdgcn_sched_barrier(0);
      __builtin_amdgcn_s_barrier();
      __builtin_amdgcn_sched_barrier(0);
      #pragma unroll
      for (int sub = 0; sub < 2; ++sub) {
        const int kv0s = it*64 + sub*32;
        if (kv0s <= qb + QW - 1) {
          f32x16 sc = (f32x16)0.0f;
          #pragma unroll
          for (int ks = 0; ks < 4; ++ks) {
            const int kvr = sub*32 + ln;
            bf16x8 af = *(const bf16x8*)(kb + SWZ(kvr, ks*32 + hi*16));
            sc = __builtin_amdgcn_mfma_f32_32x32x16_bf16(af, qf[ks], sc, 0, 0, 0);
          }
          if (kv0s + 31 > qb) {
            #pragma unroll
            for (int r = 0; r < 16; ++r) {
              const int kvg = kv0s + (r&3) + 8*(r>>2) + 4*hi;
              sc[r] = (kvg > qg) ? 0.0f : fast_exp2(sc[r]);
            }
          } else {
            #pragma unroll
            for (int r = 0; r < 16; ++r) sc[r] = fast_exp2(sc[r]);
          }
          float s0_ = (sc[0]+sc[1])+(sc[2]+sc[3]);
          float s1_ = (sc[4]+sc[5])+(sc[6]+sc[7]);
          float s2_ = (sc[8]+sc[9])+(sc[10]+sc[11]);
          float s3_ = (sc[12]+sc[13])+(sc[14]+sc[15]);
          float ls = (s0_+s1_)+(s2_+s3_);
          ls += __shfl_xor(ls, 32);
          l_run += ls;
          unsigned c0 = pk2(sc[0],sc[1]),   c1 = pk2(sc[2],sc[3]);
          unsigned c2 = pk2(sc[4],sc[5]),   c3 = pk2(sc[6],sc[7]);
          unsigned c4 = pk2(sc[8],sc[9]),   c5 = pk2(sc[10],sc[11]);
          unsigned c6 = pk2(sc[12],sc[13]), c7 = pk2(sc[14],sc[15]);
          pswap(c0, c2);  pswap(c1, c3);
          pswap(c4, c6);  pswap(c5, c7);
          Pfrag pa0, pa1;
          pa0.u[0]=c0; pa0.u[1]=c1; pa0.u[2]=c2; pa0.u[3]=c3;
          pa1.u[0]=c4; pa1.u[1]=c5; pa1.u[2]=c6; pa1.u[3]=c7;
          #pragma unroll
          for (int dt = 0; dt < 2; ++dt) {
            const int dr = dt*32 + ln;
            #pragma unroll
            for (int ks2 = 0; ks2 < 2; ++ks2) {
              bf16x8 av = *(const bf16x8*)(vb + SWZ(dr, sub*64 + ks2*32 + hi*16));
              oacc[dt] = __builtin_amdgcn_mfma_f32_32x32x16_bf16(
                  av, ks2 ? pa1.v : pa0.v, oacc[dt], 0, 0, 0);
            }
          }
        }
      }
      cur ^= 1;
    }
    const float inv = 1.0f / l_run;
    float* op = Ob + (size_t)(qb + ln) * HE;
    #pragma unroll
    for (int dt = 0; dt < 2; ++dt)
      #pragma unroll
      for (int rq = 0; rq < 4; ++rq) {
        f32x4 w;
        w[0]=oacc[dt][rq*4+0]*inv; w[1]=oacc[dt][rq*4+1]*inv;
        w[2]=oacc[dt][rq*4+2]*inv; w[3]=oacc[dt][rq*4+3]*inv;
        *(f32x4*)(op + dt*32 + 8*rq + 4*hi) = w;
      }
  }
}

extern "C" void kernel_launch(void* const* d_in, const int* in_sizes, int n_in,
                              void* d_out, int out_size, void* d_ws, size_t ws_size,
                              hipStream_t stream) {
  const float* Q = (const float*)d_in[0];
  const float* K = (const float*)d_in[1];
  const float* V = (const float*)d_in[2];
  float* O = (float*)d_out;
  if (ws_size >= WS_NEED) {
    fa_stage<<<dim3(NBH * NKT), dim3(256), 0, stream>>>(K, V, (unsigned char*)d_ws);
    fa_fwd<<<dim3(NBH * NQT), dim3(256), 0, stream>>>(   // 1024 blocks, LPT
        Q, (const unsigned char*)d_ws, O);
  } else {
    fa_fwd_fused<<<dim3(NB * NH * 8), dim3(256), 0, stream>>>(Q, K, V, O);
  }
}

// Round 25
// 71.105 us; speedup vs baseline: 2.1691x; 1.0265x over previous
//
#include <hip/hip_runtime.h>
#include <hip/hip_bf16.h>

typedef __attribute__((ext_vector_type(8))) short bf16x8;
typedef __attribute__((ext_vector_type(4))) short bf16x4;
typedef __attribute__((ext_vector_type(4))) float f32x4;
typedef __attribute__((ext_vector_type(16))) float f32x16;

#define NB 4
#define NL 2048
#define NH 16
#define NE 64
#define HE (NH*NE)
#define QW 32
#define QBLK 128
#define NQT (NL/QBLK)      // 16
#define NBH 64
#define NKT 32             // kv64 tiles per (b,h)
#define TILE_IMG 16384     // 8KB K + 8KB V^T per (bh, kv-tile)
#define WS_NEED ((size_t)NBH * NKT * TILE_IMG)   // 32 MB
#define QSCALE (0.125f * 1.44269504088896340736f)  // 1/sqrt(64) * log2(e)

union Pfrag { unsigned u[4]; bf16x8 v; };

__device__ __forceinline__ unsigned pk2(float a, float b) {
  float2 t; t.x = a; t.y = b;
  __hip_bfloat162 hh = __float22bfloat162_rn(t);    // v_cvt_pk_bf16_f32
  union { __hip_bfloat162 h; unsigned u; } v; v.h = hh;
  return v.u;                                        // a lo16, b hi16
}
#if defined(__has_builtin) && __has_builtin(__builtin_amdgcn_exp2f)
__device__ __forceinline__ float fast_exp2(float x) {
  return __builtin_amdgcn_exp2f(x);
}
#else
__device__ __forceinline__ float fast_exp2(float x) { return exp2f(x); }
#endif
__device__ __forceinline__ void pswap(unsigned &a, unsigned &b) {
  auto r = __builtin_amdgcn_permlane32_swap(a, b, false, false);
  a = r[0]; b = r[1];
}
#define SWZ(row,col) ((row)*128 + ((col) ^ ((((row) ^ ((row)>>2)) & 7) << 4)))

__device__ __forceinline__ void cp16(unsigned char* lds, const unsigned char* g) {
  __builtin_amdgcn_global_load_lds(
      (const __attribute__((address_space(1))) unsigned int*)g,
      (__attribute__((address_space(3))) unsigned int*)lds, 16, 0, 0);
}

// ---------------- prologue: build bf16 staged tile images in ws ----------------
__global__ __launch_bounds__(256) void fa_stage(
    const float* __restrict__ K, const float* __restrict__ V,
    unsigned char* __restrict__ img)
{
  const int tid = threadIdx.x;
  const int bid = blockIdx.x;
  const int bh  = bid >> 5;
  const int t0  = bid & 31;
  const int h = bh & (NH-1), b = bh >> 4;
  const size_t base = ((size_t)b * NL * NH + h) * NE + (size_t)(t0 * 64) * HE;
  unsigned char* kimg = img + (size_t)(bh * NKT + t0) * TILE_IMG;
  unsigned char* vimg = kimg + 8192;
  #pragma unroll
  for (int rep = 0; rep < 2; ++rep) {
    const int idx = rep * 256 + tid;
    const int row = idx >> 3, gr = idx & 7;
    const float* kp = K + base + (size_t)row * HE + gr * 8;
    f32x4 a0 = *(const f32x4*)kp;
    f32x4 a1 = *(const f32x4*)(kp + 4);
    Pfrag w;
    w.u[0] = pk2(a0[0], a0[1]); w.u[1] = pk2(a0[2], a0[3]);
    w.u[2] = pk2(a1[0], a1[1]); w.u[3] = pk2(a1[2], a1[3]);
    *(bf16x8*)(kimg + SWZ(row, gr * 16)) = w.v;
  }
  const int trow = tid >> 4, tcol = (tid & 15) * 4, sq = trow * 4;
  f32x4 vr[4];
  #pragma unroll
  for (int i = 0; i < 4; ++i)
    vr[i] = *(const f32x4*)(V + base + (size_t)(sq + i) * HE + tcol);
  #pragma unroll
  for (int j = 0; j < 4; ++j) {
    const int er = tcol + j;
    union { unsigned u[2]; bf16x4 v; } w;
    w.u[0] = pk2(vr[0][j], vr[1][j]);
    w.u[1] = pk2(vr[2][j], vr[3][j]);
    *(bf16x4*)(vimg + SWZ(er, sq * 2)) = w.v;
  }
}

// PACK into P frags (cvt_pk + pswap)
#define PACK(SC, PA0, PA1)                                                     \
      {                                                                        \
        unsigned c0 = pk2(SC[0],SC[1]),   c1 = pk2(SC[2],SC[3]);               \
        unsigned c2 = pk2(SC[4],SC[5]),   c3 = pk2(SC[6],SC[7]);               \
        unsigned c4 = pk2(SC[8],SC[9]),   c5 = pk2(SC[10],SC[11]);             \
        unsigned c6 = pk2(SC[12],SC[13]), c7 = pk2(SC[14],SC[15]);             \
        pswap(c0, c2);  pswap(c1, c3);                                         \
        pswap(c4, c6);  pswap(c5, c7);                                         \
        PA0.u[0]=c0; PA0.u[1]=c1; PA0.u[2]=c2; PA0.u[3]=c3;                    \
        PA1.u[0]=c4; PA1.u[1]=c5; PA1.u[2]=c6; PA1.u[3]=c7;                    \
      }

#define LSUM(LR, SC)                                                           \
      LR += ((((SC[0]+SC[1])+(SC[2]+SC[3]))+((SC[4]+SC[5])+(SC[6]+SC[7])))     \
          + (((SC[8]+SC[9])+(SC[10]+SC[11]))+((SC[12]+SC[13])+(SC[14]+SC[15]))));

// PV for a pipeline: 8 reg-only MFMAs into OACC
#define PVDO(OACC, P00, P01, P10, P11, VV)                                     \
    {                                                                          \
      _Pragma("unroll")                                                        \
      for (int dt = 0; dt < 2; ++dt) {                                         \
        OACC[dt] = __builtin_amdgcn_mfma_f32_32x32x16_bf16(                    \
            VV[0][dt], P00.v, OACC[dt], 0, 0, 0);                              \
        OACC[dt] = __builtin_amdgcn_mfma_f32_32x32x16_bf16(                    \
            VV[2][dt], P10.v, OACC[dt], 0, 0, 0);                              \
        OACC[dt] = __builtin_amdgcn_mfma_f32_32x32x16_bf16(                    \
            VV[1][dt], P01.v, OACC[dt], 0, 0, 0);                              \
        OACC[dt] = __builtin_amdgcn_mfma_f32_32x32x16_bf16(                    \
            VV[3][dt], P11.v, OACC[dt], 0, 0, 0);                              \
      }                                                                        \
    }

// QK + softmax + pack for tile IT from buf BUF; results to P*, V to VV regs
#define QKSM(IT, BUF, LR, P00, P01, P10, P11, VV)                              \
    {                                                                          \
      const unsigned char* kb = &k_lds[BUF][0];                                \
      const unsigned char* vbp = &v_lds[BUF][0];                               \
      const int kv0 = (IT)*64;                                                 \
      if (kv0 + 63 <= qb) {                                                    \
        f32x16 sc0 = (f32x16)0.0f, sc1 = (f32x16)0.0f;                         \
        _Pragma("unroll")                                                      \
        for (int ks = 0; ks < 4; ++ks) {                                       \
          bf16x8 af0 = *(const bf16x8*)(kb + addr4[ks]);                       \
          bf16x8 af1 = *(const bf16x8*)(kb + addr4[ks] + 4096);                \
          sc0 = __builtin_amdgcn_mfma_f32_32x32x16_bf16(af0, qf[ks], sc0,0,0,0);\
          sc1 = __builtin_amdgcn_mfma_f32_32x32x16_bf16(af1, qf[ks], sc1,0,0,0);\
        }                                                                      \
        _Pragma("unroll")                                                      \
        for (int r = 0; r < 16; ++r) sc0[r] = fast_exp2(sc0[r]);               \
        _Pragma("unroll")                                                      \
        for (int r = 0; r < 16; ++r) sc1[r] = fast_exp2(sc1[r]);               \
        LSUM(LR, sc0)                                                          \
        LSUM(LR, sc1)                                                          \
        PACK(sc0, P00, P01)                                                    \
        PACK(sc1, P10, P11)                                                    \
      } else {                                                                 \
        if (kv0 <= qb + 31) {                                                  \
          f32x16 sc = (f32x16)0.0f;                                            \
          _Pragma("unroll")                                                    \
          for (int ks = 0; ks < 4; ++ks) {                                     \
            bf16x8 af = *(const bf16x8*)(kb + addr4[ks]);                      \
            sc = __builtin_amdgcn_mfma_f32_32x32x16_bf16(af, qf[ks], sc,0,0,0);\
          }                                                                    \
          _Pragma("unroll")                                                    \
          for (int r = 0; r < 16; ++r) {                                       \
            const int kvg = kv0 + (r&3) + 8*(r>>2) + 4*hi;                     \
            sc[r] = (kvg > qg) ? 0.0f : fast_exp2(sc[r]);                      \
          }                                                                    \
          LSUM(LR, sc)                                                         \
          PACK(sc, P00, P01)                                                   \
        } else {                                                               \
          P00.u[0]=0; P00.u[1]=0; P00.u[2]=0; P00.u[3]=0; P01 = P00;           \
        }                                                                      \
        if (kv0 + 32 <= qb + 31) {                                             \
          f32x16 sc = (f32x16)0.0f;                                            \
          _Pragma("unroll")                                                    \
          for (int ks = 0; ks < 4; ++ks) {                                     \
            bf16x8 af = *(const bf16x8*)(kb + addr4[ks] + 4096);               \
            sc = __builtin_amdgcn_mfma_f32_32x32x16_bf16(af, qf[ks], sc,0,0,0);\
          }                                                                    \
          _Pragma("unroll")                                                    \
          for (int r = 0; r < 16; ++r) {                                       \
            const int kvg = kv0 + 32 + (r&3) + 8*(r>>2) + 4*hi;                \
            sc[r] = (kvg > qg) ? 0.0f : fast_exp2(sc[r]);                      \
          }                                                                    \
          LSUM(LR, sc)                                                         \
          PACK(sc, P10, P11)                                                   \
        } else {                                                               \
          P10.u[0]=0; P10.u[1]=0; P10.u[2]=0; P10.u[3]=0; P11 = P10;           \
        }                                                                      \
      }                                                                        \
      _Pragma("unroll")                                                        \
      for (int j = 0; j < 4; ++j) {                                            \
        VV[j][0] = *(const bf16x8*)(vbp + addr4[j]);                           \
        VV[j][1] = *(const bf16x8*)(vbp + addr4[j] + 4096);                    \
      }                                                                        \
    }

// superstep: ONE barrier, TWO INDEPENDENT tile pipelines (even=T, odd=T+1);
// prefetch tiles T+2,T+3 into bufs B0^2,B1^2 (disjoint from readers)
#define SUPER(T, B0, B1)                                                       \
    {                                                                          \
      asm volatile("s_waitcnt vmcnt(0) lgkmcnt(0)" ::: "memory");              \
      __builtin_amdgcn_sched_barrier(0);                                       \
      __builtin_amdgcn_s_barrier();                                            \
      __builtin_amdgcn_sched_barrier(0);                                       \
      if ((T) + 2 < nt) {                                                      \
        unsigned char* kd = &k_lds[(B0)^2][0];                                 \
        unsigned char* vd = &v_lds[(B0)^2][0];                                 \
        cp16(kd + wb,        src_pf);                                          \
        cp16(kd + 4096 + wb, src_pf + 4096);                                   \
        cp16(vd + wb,        src_pf + 8192);                                   \
        cp16(vd + 4096 + wb, src_pf + 12288);                                  \
        src_pf += TILE_IMG;                                                    \
        if ((T) + 3 < nt) {                                                    \
          unsigned char* kd2 = &k_lds[(B1)^2][0];                              \
          unsigned char* vd2 = &v_lds[(B1)^2][0];                              \
          cp16(kd2 + wb,        src_pf);                                       \
          cp16(kd2 + 4096 + wb, src_pf + 4096);                                \
          cp16(vd2 + wb,        src_pf + 8192);                                \
          cp16(vd2 + 4096 + wb, src_pf + 12288);                               \
          src_pf += TILE_IMG;                                                  \
        }                                                                      \
      }                                                                        \
      /* EVEN pipeline: PV(T-2) then QK/SM(T) */                               \
      if ((T) > 0) PVDO(oaccE, pe00, pe01, pe10, pe11, vvE)                    \
      QKSM((T) + 0, B0, l_runE, pe00, pe01, pe10, pe11, vvE)                   \
      /* ODD pipeline: PV(T-1) then QK/SM(T+1) — independent of EVEN */        \
      if ((T) > 0) PVDO(oaccO, po00, po01, po10, po11, vvO)                    \
      QKSM((T) + 1, B1, l_runO, po00, po01, po10, po11, vvO)                   \
    }

// ---------------- main: dual-pipeline supersteps, 1024 LPT blocks ----------------
__global__ __launch_bounds__(256, 2) void fa_fwd(
    const float* __restrict__ Q, const unsigned char* __restrict__ img,
    float* __restrict__ O)
{
  __shared__ unsigned char k_lds[4][8192];   // 4-buffer ring = 64KB total
  __shared__ unsigned char v_lds[4][8192];

  const int tid  = threadIdx.x;
  const int lane = tid & 63;
  const int wid  = tid >> 6;
  const int hi   = lane >> 5;
  const int ln   = lane & 31;

  const int bid = blockIdx.x;
  const int bh  = bid & 63;
  const int qt  = (NQT - 1) - (bid >> 6);    // LPT
  const int h   = bh & (NH-1);
  const int b   = bh >> 4;

  const size_t base = ((size_t)b * NL * NH + h) * NE;
  const float* Qb = Q + base;
  float*       Ob = O + base;
  const unsigned char* bimg = img + (size_t)bh * NKT * TILE_IMG;

  int addr4[4];
  {
    const int F = ((ln ^ (ln >> 2)) & 7) << 4;
    #pragma unroll
    for (int j = 0; j < 4; ++j) addr4[j] = ln*128 + ((j*32 + hi*16) ^ F);
  }
  const int wb = wid << 10;

  const int q0 = qt * QBLK;
  const int qb = q0 + wid * QW;
  const int nt = qt * 2 + 2;                 // even; nt%4 in {0,2}
  const int qg = qb + ln;

  // ---- Q fragments ----
  bf16x8 qf[4];
  {
    const float* qp = Qb + (size_t)(qb + ln) * HE + hi * 8;
    #pragma unroll
    for (int ks = 0; ks < 4; ++ks) {
      f32x4 a0 = *(const f32x4*)(qp + ks*16);
      f32x4 a1 = *(const f32x4*)(qp + ks*16 + 4);
      Pfrag f;
      f.u[0] = pk2(a0[0]*QSCALE, a0[1]*QSCALE);
      f.u[1] = pk2(a0[2]*QSCALE, a0[3]*QSCALE);
      f.u[2] = pk2(a1[0]*QSCALE, a1[1]*QSCALE);
      f.u[3] = pk2(a1[2]*QSCALE, a1[3]*QSCALE);
      qf[ks] = f.v;
    }
  }
  f32x16 oaccE[2], oaccO[2];
  oaccE[0] = (f32x16)0.0f; oaccE[1] = (f32x16)0.0f;
  oaccO[0] = (f32x16)0.0f; oaccO[1] = (f32x16)0.0f;
  float l_runE = 0.0f, l_runO = 0.0f;
  Pfrag pe00, pe01, pe10, pe11, po00, po01, po10, po11;
  pe00.u[0]=0;pe00.u[1]=0;pe00.u[2]=0;pe00.u[3]=0;
  pe01=pe00; pe10=pe00; pe11=pe00;
  po00=pe00; po01=pe00; po10=pe00; po11=pe00;
  bf16x8 vvE[4][2], vvO[4][2];

  // preload tiles 0,1 into bufs 0,1
  asm volatile("s_waitcnt vmcnt(0)" ::: "memory");
  __builtin_amdgcn_sched_barrier(0);
  const unsigned char* src_pf = bimg + (size_t)tid * 16;
  cp16(&k_lds[0][0] + wb,        src_pf);
  cp16(&k_lds[0][0] + 4096 + wb, src_pf + 4096);
  cp16(&v_lds[0][0] + wb,        src_pf + 8192);
  cp16(&v_lds[0][0] + 4096 + wb, src_pf + 12288);
  src_pf += TILE_IMG;
  cp16(&k_lds[1][0] + wb,        src_pf);
  cp16(&k_lds[1][0] + 4096 + wb, src_pf + 4096);
  cp16(&v_lds[1][0] + wb,        src_pf + 8192);
  cp16(&v_lds[1][0] + 4096 + wb, src_pf + 12288);
  src_pf += TILE_IMG;

  int t0 = 0;
  #pragma unroll 1
  for (; t0 + 4 <= nt; t0 += 4) {
    SUPER(t0 + 0, 0, 1)
    SUPER(t0 + 2, 2, 3)
  }
  if (t0 < nt) SUPER(t0, 0, 1)     // nt%4==2 tail (t0%4==0 -> bufs 0,1)
  // flush both pipelines (tiles nt-2 even, nt-1 odd)
  PVDO(oaccE, pe00, pe01, pe10, pe11, vvE)
  PVDO(oaccO, po00, po01, po10, po11, vvO)

  const float l_mine = l_runE + l_runO;
  const float l_tot = l_mine + __shfl_xor(l_mine, 32);
  const float inv = 1.0f / l_tot;
  float* op = Ob + (size_t)(qb + ln) * HE;
  #pragma unroll
  for (int dt = 0; dt < 2; ++dt)
    #pragma unroll
    for (int rq = 0; rq < 4; ++rq) {
      f32x4 w;
      w[0]=(oaccE[dt][rq*4+0]+oaccO[dt][rq*4+0])*inv;
      w[1]=(oaccE[dt][rq*4+1]+oaccO[dt][rq*4+1])*inv;
      w[2]=(oaccE[dt][rq*4+2]+oaccO[dt][rq*4+2])*inv;
      w[3]=(oaccE[dt][rq*4+3]+oaccO[dt][rq*4+3])*inv;
      *(f32x4*)(op + dt*32 + 8*rq + 4*hi) = w;
    }
}

// ---------------- fused fallback (R6-style) if ws too small ----------------
__global__ __launch_bounds__(256, 3) void fa_fwd_fused(
    const float* __restrict__ Q, const float* __restrict__ K,
    const float* __restrict__ V, float* __restrict__ O)
{
  __shared__ unsigned char kf_lds[2][64*128];
  __shared__ unsigned char vf_lds[2][64*128];
  const int tid  = threadIdx.x;
  const int lane = tid & 63;
  const int wid  = tid >> 6;
  const int hi   = lane >> 5;
  const int ln   = lane & 31;
  const int trow = tid >> 4;
  const int tcol = (tid & 15) * 4;
  const int sq   = trow * 4;
  const int bidp = blockIdx.x;
  const int lb   = (bidp & 7) * 64 + (bidp >> 3);
  const int pair = lb & 7;
  const int bh   = lb >> 3;
  const int h    = bh & (NH-1);
  const int b    = bh >> 4;
  const size_t base = ((size_t)b * NL * NH + h) * NE;
  const float* Qb = Q + base;
  const float* Kb = K + base;
  const float* Vb = V + base;
  float*       Ob = O + base;
  int cur = 0;
  #pragma unroll 1
  for (int hf = 0; hf < 2; ++hf) {
    const int qt = hf ? (NQT - 1 - pair) : pair;
    const int q0 = qt * QBLK;
    const int qb = q0 + wid * QW;
    const int nt = qt * 2 + 2;
    const int qg = qb + ln;
    bf16x8 qf[4];
    {
      const float* qp = Qb + (size_t)(qb + ln) * HE + hi * 8;
      #pragma unroll
      for (int ks = 0; ks < 4; ++ks) {
        f32x4 a0 = *(const f32x4*)(qp + ks*16);
        f32x4 a1 = *(const f32x4*)(qp + ks*16 + 4);
        Pfrag f;
        f.u[0] = pk2(a0[0]*QSCALE, a0[1]*QSCALE);
        f.u[1] = pk2(a0[2]*QSCALE, a0[3]*QSCALE);
        f.u[2] = pk2(a1[0]*QSCALE, a1[1]*QSCALE);
        f.u[3] = pk2(a1[2]*QSCALE, a1[3]*QSCALE);
        qf[ks] = f.v;
      }
    }
    f32x16 oacc[2];
    oacc[0] = (f32x16)0.0f; oacc[1] = (f32x16)0.0f;
    float l_run = 0.0f;
    f32x4 kreg[4], vreg[4];
    #pragma unroll
    for (int p = 0; p < 4; ++p)
      kreg[p] = *(const f32x4*)(Kb + (size_t)(trow + p*16) * HE + tcol);
    #pragma unroll
    for (int i = 0; i < 4; ++i)
      vreg[i] = *(const f32x4*)(Vb + (size_t)(sq + i) * HE + tcol);
    #pragma unroll 1
    for (int it = 0; it < nt; ++it) {
      unsigned char* kb = kf_lds[cur];
      unsigned char* vb = vf_lds[cur];
      #pragma unroll
      for (int p = 0; p < 4; ++p) {
        const int row = trow + p*16;
        union { unsigned u[2]; bf16x4 v; } w;
        w.u[0] = pk2(kreg[p][0], kreg[p][1]);
        w.u[1] = pk2(kreg[p][2], kreg[p][3]);
        *(bf16x4*)(kb + SWZ(row, tcol*2)) = w.v;
      }
      #pragma unroll
      for (int j = 0; j < 4; ++j) {
        const int er = tcol + j;
        union { unsigned u[2]; bf16x4 v; } w;
        w.u[0] = pk2(vreg[0][j], vreg[1][j]);
        w.u[1] = pk2(vreg[2][j], vreg[3][j]);
        *(bf16x4*)(vb + SWZ(er, sq*2)) = w.v;
      }
      if (it + 1 < nt) {
        const int s0 = (it + 1) * 64;
        #pragma unroll
        for (int p = 0; p < 4; ++p)
          kreg[p] = *(const f32x4*)(Kb + (size_t)(s0 + trow + p*16) * HE + tcol);
        #pragma unroll
        for (int i = 0; i < 4; ++i)
          vreg[i] = *(const f32x4*)(Vb + (size_t)(s0 + sq + i) * HE + tcol);
      }
      asm volatile("s_waitcnt lgkmcnt(0)" ::: "memory");
      __builtin_amdgcn_sched_barrier(0);
      __builtin_amdgcn_s_barrier();
      __builtin_amdgcn_sched_barrier(0);
      #pragma unroll
      for (int sub = 0; sub < 2; ++sub) {
        const int kv0s = it*64 + sub*32;
        if (kv0s <= qb + QW - 1) {
          f32x16 sc = (f32x16)0.0f;
          #pragma unroll
          for (int ks = 0; ks < 4; ++ks) {
            const int kvr = sub*32 + ln;
            bf16x8 af = *(const bf16x8*)(kb + SWZ(kvr, ks*32 + hi*16));
            sc = __builtin_amdgcn_mfma_f32_32x32x16_bf16(af, qf[ks], sc, 0, 0, 0);
          }
          if (kv0s + 31 > qb) {
            #pragma unroll
            for (int r = 0; r < 16; ++r) {
              const int kvg = kv0s + (r&3) + 8*(r>>2) + 4*hi;
              sc[r] = (kvg > qg) ? 0.0f : fast_exp2(sc[r]);
            }
          } else {
            #pragma unroll
            for (int r = 0; r < 16; ++r) sc[r] = fast_exp2(sc[r]);
          }
          float s0_ = (sc[0]+sc[1])+(sc[2]+sc[3]);
          float s1_ = (sc[4]+sc[5])+(sc[6]+sc[7]);
          float s2_ = (sc[8]+sc[9])+(sc[10]+sc[11]);
          float s3_ = (sc[12]+sc[13])+(sc[14]+sc[15]);
          float ls = (s0_+s1_)+(s2_+s3_);
          ls += __shfl_xor(ls, 32);
          l_run += ls;
          unsigned c0 = pk2(sc[0],sc[1]),   c1 = pk2(sc[2],sc[3]);
          unsigned c2 = pk2(sc[4],sc[5]),   c3 = pk2(sc[6],sc[7]);
          unsigned c4 = pk2(sc[8],sc[9]),   c5 = pk2(sc[10],sc[11]);
          unsigned c6 = pk2(sc[12],sc[13]), c7 = pk2(sc[14],sc[15]);
          pswap(c0, c2);  pswap(c1, c3);
          pswap(c4, c6);  pswap(c5, c7);
          Pfrag pa0, pa1;
          pa0.u[0]=c0; pa0.u[1]=c1; pa0.u[2]=c2; pa0.u[3]=c3;
          pa1.u[0]=c4; pa1.u[1]=c5; pa1.u[2]=c6; pa1.u[3]=c7;
          #pragma unroll
          for (int dt = 0; dt < 2; ++dt) {
            const int dr = dt*32 + ln;
            #pragma unroll
            for (int ks2 = 0; ks2 < 2; ++ks2) {
              bf16x8 av = *(const bf16x8*)(vb + SWZ(dr, sub*64 + ks2*32 + hi*16));
              oacc[dt] = __builtin_amdgcn_mfma_f32_32x32x16_bf16(
                  av, ks2 ? pa1.v : pa0.v, oacc[dt], 0, 0, 0);
            }
          }
        }
      }
      cur ^= 1;
    }
    const float inv = 1.0f / l_run;
    float* op = Ob + (size_t)(qb + ln) * HE;
    #pragma unroll
    for (int dt = 0; dt < 2; ++dt)
      #pragma unroll
      for (int rq = 0; rq < 4; ++rq) {
        f32x4 w;
        w[0]=oacc[dt][rq*4+0]*inv; w[1]=oacc[dt][rq*4+1]*inv;
        w[2]=oacc[dt][rq*4+2]*inv; w[3]=oacc[dt][rq*4+3]*inv;
        *(f32x4*)(op + dt*32 + 8*rq + 4*hi) = w;
      }
  }
}

extern "C" void kernel_launch(void* const* d_in, const int* in_sizes, int n_in,
                              void* d_out, int out_size, void* d_ws, size_t ws_size,
                              hipStream_t stream) {
  const float* Q = (const float*)d_in[0];
  const float* K = (const float*)d_in[1];
  const float* V = (const float*)d_in[2];
  float* O = (float*)d_out;
  if (ws_size >= WS_NEED) {
    fa_stage<<<dim3(NBH * NKT), dim3(256), 0, stream>>>(K, V, (unsigned char*)d_ws);
    fa_fwd<<<dim3(NBH * NQT), dim3(256), 0, stream>>>(   // 1024 blocks, LPT
        Q, (const unsigned char*)d_ws, O);
  } else {
    fa_fwd_fused<<<dim3(NB * NH * 8), dim3(256), 0, stream>>>(Q, K, V, O);
  }
}